// Round 6
// baseline (209.142 us; speedup 1.0000x reference)
//
#include <hip/hip_runtime.h>
#include <math.h>

#define B_   256
#define IN_  512
#define C_   4
#define M_   6
#define K_   64
#define S1_  255
#define S2_  63

#define NBLK1 (C_ * S1_)                 // 1020
#define NBLK2 (C_ * S2_)                 // 252
#define NBLK3 (C_)                       // 4
#define NBLK_ALL (NBLK1 + NBLK2 + NBLK3) // 1276

#define LMIN_ (-6.906754778648554f)
#define LMAX_ ( 6.906754778648554f)
#define LR_   0.001f
#define WCLIP_ 5.0f

__device__ __forceinline__ float clampf(float v, float lo, float hi) {
    return fminf(fmaxf(v, lo), hi);
}

// One-time prep: xT[i][b], l0[b][i], l0T[i][b]; bias columns of out1/out2.
__global__ __launch_bounds__(256) void prep_kernel(const float* __restrict__ x,
                                                   const float* __restrict__ bias1,
                                                   const float* __restrict__ bias2,
                                                   float* __restrict__ xT,
                                                   float* __restrict__ l0,
                                                   float* __restrict__ l0T,
                                                   float* __restrict__ out1T,
                                                   float* __restrict__ out1RM,
                                                   float* __restrict__ out2T,
                                                   float* __restrict__ out2RM) {
    __shared__ float tx_[32][33];
    __shared__ float tl_[32][33];
    const int i0 = (blockIdx.x & 15) * 32;
    const int b0 = (blockIdx.x >> 4) * 32;
    const int tx = threadIdx.x & 31;
    const int ty = threadIdx.x >> 5;
#pragma unroll
    for (int r = 0; r < 4; ++r) {
        int bb = b0 + ty + 8 * r;
        int ii = i0 + tx;
        float xv = x[(size_t)bb * IN_ + ii];
        float xc = clampf(xv, 0.001f, 0.999f);
        float lv = (ii == 0) ? 0.0f : logf(xc / (1.0f - xc));
        l0[(size_t)bb * IN_ + ii] = lv;
        tx_[ty + 8 * r][tx] = xv;
        tl_[ty + 8 * r][tx] = lv;
    }
    __syncthreads();
#pragma unroll
    for (int r = 0; r < 4; ++r) {
        int ii = i0 + ty + 8 * r;
        int bb = b0 + tx;
        xT[(size_t)ii * B_ + bb]  = tx_[tx][ty + 8 * r];
        l0T[(size_t)ii * B_ + bb] = tl_[tx][ty + 8 * r];
    }
    int gid = blockIdx.x * 256 + threadIdx.x;
    if (gid < C_ * B_) {
        int c = gid >> 8, b = gid & 255;
        float b1 = bias1[c], b2 = bias2[c];
        out1T[((size_t)c * (S1_ + 1)) * B_ + b] = b1;
        out1RM[((size_t)c * B_ + b) * (S1_ + 1)] = b1;
        out2T[((size_t)c * (S2_ + 1)) * B_ + b] = b2;
        out2RM[((size_t)c * B_ + b) * (S2_ + 1)] = b2;
    }
}

// Routing, 2 tiles per block; thread = batch b.
__global__ __launch_bounds__(256) void route_kernel(
    const float* __restrict__ xT,
    const float* __restrict__ cmaps1,
    const float* __restrict__ cmaps2,
    const float* __restrict__ cmaps3,
    int* __restrict__ idx_buf)          // [NBLK_ALL][B]
{
    const int b = threadIdx.x;
    const int t0 = blockIdx.x * 2;
    const float* cmp[2];
#pragma unroll
    for (int u = 0; u < 2; ++u) {
        int bid = t0 + u;
        if (bid < NBLK1)              cmp[u] = cmaps1 + (size_t)bid * M_ * IN_;
        else if (bid < NBLK1 + NBLK2) cmp[u] = cmaps2 + (size_t)(bid - NBLK1) * M_ * IN_;
        else                          cmp[u] = cmaps3 + (size_t)(bid - NBLK1 - NBLK2) * M_ * IN_;
    }
    float acc[2][M_];
#pragma unroll
    for (int u = 0; u < 2; ++u)
#pragma unroll
        for (int m = 0; m < M_; ++m) acc[u][m] = 0.0f;

    for (int k = 0; k < IN_; k += 8) {
        float xv[8];
#pragma unroll
        for (int j = 0; j < 8; ++j) xv[j] = xT[(size_t)(k + j) * B_ + b];
#pragma unroll
        for (int j = 0; j < 8; ++j)
#pragma unroll
            for (int u = 0; u < 2; ++u)
#pragma unroll
                for (int m = 0; m < M_; ++m)
                    acc[u][m] = fmaf(cmp[u][(size_t)m * IN_ + k + j], xv[j], acc[u][m]);
    }
#pragma unroll
    for (int u = 0; u < 2; ++u) {
        int myidx = 0;
#pragma unroll
        for (int m = 0; m < M_; ++m) myidx |= (acc[u][m] > 0.0f) ? (1 << m) : 0;
        idx_buf[(size_t)(t0 + u) * B_ + b] = myidx;
    }
}

// Phase A: partial dots. Block = (tile, DIN-split). All 256 lanes active.
template<int DIN, int DSPLIT>
__global__ __launch_bounds__(256) void dot_kernel(
    const float* __restrict__ lgT, long lgT_sc,
    const float* __restrict__ w,
    const int* __restrict__ idx_buf,
    float* __restrict__ pdot,          // [tiles][DSPLIT][B]
    int S)
{
    constexpr int PART = DIN / DSPLIT;
    constexpr int WCHv = 32;
    constexpr int NT   = PART / WCHv;
    __shared__ float wl[2][K_][WCHv + 1];

    const int tile = blockIdx.x / DSPLIT;
    const int sp   = blockIdx.x % DSPLIT;
    const int c    = tile / S;
    const int tid  = threadIdx.x;
    const int b    = tid;

    const int myrow = idx_buf[(size_t)tile * B_ + b];
    const float* wp   = w + (size_t)tile * K_ * DIN + sp * PART;
    const float* lgTc = lgT + (size_t)c * lgT_sc + (size_t)(sp * PART) * B_;

    const int srow = tid >> 2;               // staging: 64 rows, 4 threads/row? no:
    // mapping: f in [0,512): row=f>>3, quad=(f&7)<<2  (8 f4 = 32 floats per row)
    float4 pre0, pre1;
#define LOADCH(t)                                                              \
    {                                                                          \
        const float* src = wp + (size_t)(t) * WCHv;                            \
        int f0 = tid;       int r0v = f0 >> 3; int k0v = (f0 & 7) << 2;        \
        int f1 = tid + 256; int r1v = f1 >> 3; int k1v = (f1 & 7) << 2;        \
        pre0 = *(const float4*)(src + (size_t)r0v * DIN + k0v);                \
        pre1 = *(const float4*)(src + (size_t)r1v * DIN + k1v);                \
    }
#define WRITECH(buf)                                                           \
    {                                                                          \
        int f0 = tid;       int r0v = f0 >> 3; int k0v = (f0 & 7) << 2;        \
        int f1 = tid + 256; int r1v = f1 >> 3; int k1v = (f1 & 7) << 2;        \
        wl[buf][r0v][k0v + 0] = pre0.x; wl[buf][r0v][k0v + 1] = pre0.y;        \
        wl[buf][r0v][k0v + 2] = pre0.z; wl[buf][r0v][k0v + 3] = pre0.w;        \
        wl[buf][r1v][k1v + 0] = pre1.x; wl[buf][r1v][k1v + 1] = pre1.y;        \
        wl[buf][r1v][k1v + 2] = pre1.z; wl[buf][r1v][k1v + 3] = pre1.w;        \
    }
    (void)srow;
    LOADCH(0)
    float dot = 0.0f;
    for (int t = 0; t < NT; ++t) {
        const int cur = t & 1;
        WRITECH(cur)
        if (t + 1 < NT) LOADCH(t + 1)
        __syncthreads();
#pragma unroll
        for (int kk = 0; kk < WCHv; ++kk)
            dot = fmaf(wl[cur][myrow][kk], lgTc[(size_t)(t * WCHv + kk) * B_ + b], dot);
        __syncthreads();
    }
    pdot[((size_t)tile * DSPLIT + sp) * B_ + b] = dot;
#undef LOADCH
#undef WRITECH
}

// Finalize: sum partials, clip, outputs, sigmoid-diff, winner, per-row dw.
__global__ __launch_bounds__(256) void fin_kernel(
    const float* __restrict__ pdot, int DSPLIT,
    const int* __restrict__ idx_buf,
    const int* __restrict__ target,
    float* __restrict__ onextT,        // [c][S+1][b] (null if last)
    float* __restrict__ onextRM,       // [c][b][S+1] or logits[b][C]
    int* __restrict__ win_g,           // [tiles][K]
    float* __restrict__ dw_g,          // [tiles][K]
    int S, int is_last)
{
    __shared__ float diff_s[B_];
    __shared__ int   win_s[K_];
    const int tile = blockIdx.x;
    const int c    = tile / S;
    const int s    = tile - c * S;
    const int b    = threadIdx.x;

    if (b < K_) win_s[b] = -1;

    float dot = 0.0f;
    for (int j = 0; j < DSPLIT; ++j)
        dot += pdot[((size_t)tile * DSPLIT + j) * B_ + b];

    float outv = clampf(dot, LMIN_, LMAX_);
    if (is_last) {
        onextRM[(size_t)b * C_ + c] = outv;
    } else {
        onextT[((size_t)c * (S + 1) + (s + 1)) * B_ + b] = outv;
        onextRM[((size_t)c * B_ + b) * (size_t)(S + 1) + (s + 1)] = outv;
    }
    float tg = (target[b] == c) ? 1.0f : 0.0f;
    diff_s[b] = 1.0f / (1.0f + expf(-outv)) - tg;
    const int myrow = idx_buf[(size_t)tile * B_ + b];
    __syncthreads();
    atomicMax(&win_s[myrow], b);         // last-b-wins == max b
    __syncthreads();
    if (b < K_) {
        int bw = win_s[b];
        win_g[(size_t)tile * K_ + b] = bw;
        dw_g[(size_t)tile * K_ + b]  = (bw >= 0) ? LR_ * diff_s[bw] : 0.0f;
    }
}

// Phase B: pure stream update. thread -> float4; 8 per thread.
template<int DIN>
__global__ __launch_bounds__(256) void update_kernel(
    const float* __restrict__ w,
    const float* __restrict__ lgRM, long lg_sc,
    const int* __restrict__ win_g,
    const float* __restrict__ dw_g,
    float* __restrict__ nw,
    int SK)                            // S * K_ (rows per class)
{
    constexpr int QPR  = DIN / 4;
    constexpr int QSH  = (DIN == 512) ? 7 : (DIN == 256) ? 6 : 4;
    const int base = blockIdx.x * 2048 + threadIdx.x;
#pragma unroll
    for (int j = 0; j < 8; ++j) {
        int Q   = base + j * 256;
        int row = Q >> QSH;
        int col = (Q & (QPR - 1)) << 2;
        float4 wv = *(const float4*)(w + (size_t)row * DIN + col);
        int bw = win_g[row];
        if (bw >= 0) {
            float d = dw_g[row];
            int cc  = row / SK;
            const float4 lv = *(const float4*)(lgRM + (size_t)cc * lg_sc + (size_t)bw * DIN + col);
            wv.x = clampf(wv.x - d * lv.x, -WCLIP_, WCLIP_);
            wv.y = clampf(wv.y - d * lv.y, -WCLIP_, WCLIP_);
            wv.z = clampf(wv.z - d * lv.z, -WCLIP_, WCLIP_);
            wv.w = clampf(wv.w - d * lv.w, -WCLIP_, WCLIP_);
        }
        *(float4*)(nw + (size_t)row * DIN + col) = wv;
    }
}

extern "C" void kernel_launch(void* const* d_in, const int* in_sizes, int n_in,
                              void* d_out, int out_size, void* d_ws, size_t ws_size,
                              hipStream_t stream) {
    const float* x      = (const float*)d_in[0];
    const int*   target = (const int*)  d_in[1];
    const float* cmaps1 = (const float*)d_in[2];
    const float* w1     = (const float*)d_in[3];
    const float* bias1  = (const float*)d_in[4];
    const float* cmaps2 = (const float*)d_in[5];
    const float* w2     = (const float*)d_in[6];
    const float* bias2  = (const float*)d_in[7];
    const float* cmaps3 = (const float*)d_in[8];
    const float* w3     = (const float*)d_in[9];
    float* out = (float*)d_out;

    float* xT      = (float*)d_ws;                           // 131072
    float* l0      = xT     + (size_t)IN_ * B_;              // 131072
    float* l0T     = l0     + (size_t)B_ * IN_;              // 131072
    float* out1T   = l0T    + (size_t)IN_ * B_;              // 262144
    float* out1RM  = out1T  + (size_t)C_ * (S1_ + 1) * B_;   // 262144
    float* out2T   = out1RM + (size_t)C_ * B_ * (S1_ + 1);   // 65536
    float* out2RM  = out2T  + (size_t)C_ * (S2_ + 1) * B_;   // 65536
    float* pdot    = out2RM + (size_t)C_ * B_ * (S2_ + 1);   // 1020*2*256 = 522240
    float* dw_g    = pdot   + (size_t)NBLK1 * 2 * B_;        // NBLK_ALL*K
    int*   win_g   = (int*)(dw_g + (size_t)NBLK_ALL * K_);   // NBLK_ALL*K
    int*   idx_buf = (int*)(win_g + (size_t)NBLK_ALL * K_);  // NBLK_ALL*B

    float* logits = out;
    float* nw1 = out + (size_t)B_ * C_;
    float* nw2 = nw1 + (size_t)C_ * S1_ * K_ * IN_;
    float* nw3 = nw2 + (size_t)C_ * S2_ * K_ * (S1_ + 1);

    prep_kernel<<<dim3(128), dim3(256), 0, stream>>>(
        x, bias1, bias2, xT, l0, l0T, out1T, out1RM, out2T, out2RM);

    route_kernel<<<dim3(NBLK_ALL / 2), dim3(256), 0, stream>>>(
        xT, cmaps1, cmaps2, cmaps3, idx_buf);

    const int*   idx1 = idx_buf;
    const int*   idx2 = idx_buf + (size_t)NBLK1 * B_;
    const int*   idx3 = idx_buf + (size_t)(NBLK1 + NBLK2) * B_;
    int*   win1 = win_g;                float* dw1 = dw_g;
    int*   win2 = win_g + NBLK1 * K_;   float* dw2 = dw_g + NBLK1 * K_;
    int*   win3 = win_g + (NBLK1 + NBLK2) * K_;
    float* dw3  = dw_g  + (NBLK1 + NBLK2) * K_;

    // ---- layer 1 (DIN=512, lg = l0, c-stride 0) ----
    dot_kernel<512, 2><<<dim3(NBLK1 * 2), dim3(256), 0, stream>>>(
        l0T, 0L, w1, idx1, pdot, S1_);
    fin_kernel<<<dim3(NBLK1), dim3(256), 0, stream>>>(
        pdot, 2, idx1, target, out1T, out1RM, win1, dw1, S1_, 0);
    update_kernel<512><<<dim3(NBLK1 * K_ * 128 / 2048), dim3(256), 0, stream>>>(
        w1, l0, 0L, win1, dw1, nw1, S1_ * K_);

    // ---- layer 2 (DIN=256, lg = out1) ----
    dot_kernel<256, 4><<<dim3(NBLK2 * 4), dim3(256), 0, stream>>>(
        out1T, (long)(S1_ + 1) * B_, w2, idx2, pdot, S2_);
    fin_kernel<<<dim3(NBLK2), dim3(256), 0, stream>>>(
        pdot, 4, idx2, target, out2T, out2RM, win2, dw2, S2_, 0);
    update_kernel<256><<<dim3(NBLK2 * K_ * 64 / 2048), dim3(256), 0, stream>>>(
        w2, out1RM, (long)B_ * (S1_ + 1), win2, dw2, nw2, S2_ * K_);

    // ---- layer 3 (DIN=64, lg = out2) ----
    dot_kernel<64, 1><<<dim3(NBLK3), dim3(256), 0, stream>>>(
        out2T, (long)(S2_ + 1) * B_, w3, idx3, pdot, 1);
    fin_kernel<<<dim3(NBLK3), dim3(256), 0, stream>>>(
        pdot, 1, idx3, target, nullptr, logits, win3, dw3, 1, 1);
    update_kernel<64><<<dim3(NBLK3 * K_ * 16 / 2048), dim3(256), 0, stream>>>(
        w3, out2RM, (long)B_ * (S2_ + 1), win3, dw3, nw3, 1 * K_);
}